// Round 5
// baseline (416.128 us; speedup 1.0000x reference)
//
#include <hip/hip_runtime.h>
#include <stdint.h>
#include <stddef.h>

#define HIDDEN 2048
#define INTER  5632
#define TOKENS 4096   // B*S = 2*2048
#define BK     64     // f16 K-tile (down GEMM)  -> 128B rows, 88 iters
#define BKI    64     // i8 K-tile (gateup GEMM) -> 64B rows, 32 iters

typedef __attribute__((ext_vector_type(8))) _Float16 f16x8;
typedef __attribute__((ext_vector_type(4))) _Float16 f16x4;
typedef __attribute__((ext_vector_type(4))) float    f32x4;
typedef __attribute__((ext_vector_type(4))) int      i32x4;

// 128B-row LDS swizzle, period-8 row rotation: global segment q of row r lives
// at slot r*8 + ((q + r) & 7).  ds_read_b128 conflict unit is an 8-lane phase
// (8 x 16B = all 32 banks): for fixed q, 8 consecutive rows map to 8 DISTINCT
// bank-quads -> conflict-free (HW-verified: SQ_LDS_BANK_CONFLICT = 0, R0/R3/R4).
__device__ __forceinline__ int swz8(int row, int q) {
    return row * 8 + ((q + row) & 7);
}

// 64B-row PAIRED layout: two matrix rows share one 128B LDS row.
// slot(m,q) = (m>>1)*8 + (m&1)*4 + ((q + (m>>1)) & 3).
// 8-lane read phase (fixed q, rows m..m+7) hits 8 distinct bank-quads.
// HW-verified R2: SQ_LDS_BANK_CONFLICT = 0, results correct.
__device__ __forceinline__ int slotGU(int m, int q) {
    return (m >> 1) * 8 + (m & 1) * 4 + ((q + (m >> 1)) & 3);
}

#define GLDS16(g, l) __builtin_amdgcn_global_load_lds( \
    (__attribute__((address_space(1))) void*)(g), \
    (__attribute__((address_space(3))) void*)(l), 16, 0, 0)

// ---------------------------------------------------------------------------
// fused prepass: blocks [0,TOKENS) quantize x per-token to i8;
// blocks [TOKENS, TOKENS+2048) grid-stride convert weights
// ---------------------------------------------------------------------------
__global__ __launch_bounds__(256)
void prepass(const float* __restrict__ x,
             const float4* __restrict__ gw, const float4* __restrict__ uw,
             const float4* __restrict__ dw,
             int8_t* __restrict__ xq, float* __restrict__ xs,
             int* __restrict__ go, int* __restrict__ uo,
             f16x4* __restrict__ dno) {
    const int tid = threadIdx.x;
    if (blockIdx.x < TOKENS) {
        const int t = blockIdx.x;
        const float4* row = (const float4*)(x + (size_t)t * HIDDEN);
        float4 v0 = row[tid * 2];
        float4 v1 = row[tid * 2 + 1];
        float m = fmaxf(fmaxf(fabsf(v0.x), fabsf(v0.y)), fmaxf(fabsf(v0.z), fabsf(v0.w)));
        m = fmaxf(m, fmaxf(fmaxf(fabsf(v1.x), fabsf(v1.y)), fmaxf(fabsf(v1.z), fabsf(v1.w))));
        #pragma unroll
        for (int off = 32; off; off >>= 1)
            m = fmaxf(m, __shfl_xor(m, off, 64));
        __shared__ float wmax[4];
        if ((tid & 63) == 0) wmax[tid >> 6] = m;
        __syncthreads();
        m = fmaxf(fmaxf(wmax[0], wmax[1]), fmaxf(wmax[2], wmax[3]));
        m = fmaxf(m, 1e-20f);
        if (tid == 0) xs[t] = m * (1.0f / 127.0f);
        const float inv = 127.0f / m;
        float vals[8] = {v0.x, v0.y, v0.z, v0.w, v1.x, v1.y, v1.z, v1.w};
        int b[8];
        #pragma unroll
        for (int i = 0; i < 8; ++i) b[i] = (int)rintf(vals[i] * inv);
        int lo = (b[0] & 255) | ((b[1] & 255) << 8) | ((b[2] & 255) << 16) | (b[3] << 24);
        int hi = (b[4] & 255) | ((b[5] & 255) << 8) | ((b[6] & 255) << 16) | (b[7] << 24);
        ((int2*)(xq + (size_t)t * HIDDEN))[tid] = make_int2(lo, hi);
        return;
    }
    const int NW4 = INTER * HIDDEN / 4;
    int i = (blockIdx.x - TOKENS) * blockDim.x + tid;
    const int stride = 2048 * blockDim.x;
    for (; i < 3 * NW4; i += stride) {
        if (i < 2 * NW4) {
            const bool is_g = i < NW4;
            const int j = is_g ? i : i - NW4;
            float4 f = is_g ? gw[j] : uw[j];
            int p = ((int)(signed char)(int)f.x & 255)
                  | (((int)(signed char)(int)f.y & 255) << 8)
                  | (((int)(signed char)(int)f.z & 255) << 16)
                  | (((int)(signed char)(int)f.w) << 24);
            if (is_g) go[j] = p; else uo[j] = p;
        } else {
            const int j = i - 2 * NW4;
            float4 f = dw[j];
            f16x4 o;
            o.x = (_Float16)f.x; o.y = (_Float16)f.y;
            o.z = (_Float16)f.z; o.w = (_Float16)f.w;
            dno[j] = o;
        }
    }
}

// ---------------------------------------------------------------------------
// GEMM1 fused (i8): H = silu(G*xs*gs) * (U*xs*us)  (fp16 out)
// 128x128 tile, BKI=64 (32 K-iters), LDS 24KB -> 5-6 resident blocks/CU
// (was 48KB -> 2).  R0 2-barrier structure verbatim (R1/R3 in-block pipeline
// attempts both regressed; overlap comes from ANTI-PHASE co-resident blocks,
// m114).  Paired-row slotGU layout for 64B rows (R2 HW-verified: 0 conflicts,
// correct).  (256,2) bounds: floor not cap -> no R2-style spill.
// ---------------------------------------------------------------------------
__global__ __launch_bounds__(256, 2)
void gemm_gateup(const int8_t* __restrict__ Xq,
                 const int8_t* __restrict__ Wg,
                 const int8_t* __restrict__ Wu,
                 const float* __restrict__ xs,
                 const float* __restrict__ gs,
                 const float* __restrict__ us,
                 _Float16* __restrict__ Hm) {
    __shared__ int8_t As [128 * BKI];   // 8KB
    __shared__ int8_t Bgs[128 * BKI];   // 8KB
    __shared__ int8_t Bus[128 * BKI];   // 8KB

    // XCD-chunked bijective swizzle (nwg = 1408 = 8*176)
    const int pid   = (blockIdx.x % 8) * 176 + blockIdx.x / 8;
    const int local = pid % (16 * 44);
    const int bm    = ((pid / (16 * 44)) * 16 + (local & 15)) * 128;
    const int bn    = (local >> 4) * 128;

    const int tid  = threadIdx.x;
    const int lane = tid & 63;
    const int wave = tid >> 6;
    const int wm   = (wave >> 1) * 64;
    const int wn   = (wave & 1) * 64;
    const int l15  = lane & 15;
    const int lq   = lane >> 4;

    // staging: 512 16B-slots per matrix per tile; slot f (paired-row layout):
    // row = 2*(f>>3) + ((f>>2)&1), seg = ((f&3) - (f>>3)) & 3.
    int rowS[2], segS[2];
    #pragma unroll
    for (int j = 0; j < 2; ++j) {
        const int f = tid + 256 * j;
        rowS[j] = 2 * (f >> 3) + ((f >> 2) & 1);
        segS[j] = (((f & 3) - (f >> 3)) & 3) * 16;
    }

    const int8_t* gA = Xq + (size_t)bm * HIDDEN;
    const int8_t* gG = Wg + (size_t)bn * HIDDEN;
    const int8_t* gU = Wu + (size_t)bn * HIDDEN;

    i32x4 accg[4][4] = {};
    i32x4 accu[4][4] = {};

    for (int k0 = 0; k0 < HIDDEN; k0 += BKI) {
        #pragma unroll
        for (int j = 0; j < 2; ++j) {
            const int f = tid + 256 * j;
            const size_t off = (size_t)rowS[j] * HIDDEN + k0 + segS[j];
            GLDS16(gA + off, &As [f * 16]);
            GLDS16(gG + off, &Bgs[f * 16]);
            GLDS16(gU + off, &Bus[f * 16]);
        }
        __syncthreads();

        i32x4 a[4];
        #pragma unroll
        for (int im = 0; im < 4; ++im)
            a[im] = *(const i32x4*)&As[slotGU(wm + im * 16 + l15, lq) * 16];
        #pragma unroll
        for (int jn = 0; jn < 4; ++jn) {
            i32x4 bg = *(const i32x4*)&Bgs[slotGU(wn + jn * 16 + l15, lq) * 16];
            i32x4 bu = *(const i32x4*)&Bus[slotGU(wn + jn * 16 + l15, lq) * 16];
            #pragma unroll
            for (int im = 0; im < 4; ++im) {
                accg[im][jn] = __builtin_amdgcn_mfma_i32_16x16x64_i8(a[im], bg, accg[im][jn], 0, 0, 0);
                accu[im][jn] = __builtin_amdgcn_mfma_i32_16x16x64_i8(a[im], bu, accu[im][jn], 0, 0, 0);
            }
        }
        __syncthreads();
    }

    #pragma unroll
    for (int jn = 0; jn < 4; ++jn) {
        const int col = bn + wn + jn * 16 + l15;
        const float sg = gs[col];
        const float su = us[col];
        #pragma unroll
        for (int im = 0; im < 4; ++im) {
            const int rbase = bm + wm + im * 16 + lq * 4;
            #pragma unroll
            for (int r = 0; r < 4; ++r) {
                const int row = rbase + r;
                const float st = xs[row];
                float g = (float)accg[im][jn][r] * st * sg;
                float u = (float)accu[im][jn][r] * st * su;
                float h = (g / (1.0f + __expf(-g))) * u;
                Hm[(size_t)row * INTER + col] = (_Float16)h;
            }
        }
    }
}

// ---------------------------------------------------------------------------
// GEMM2 (fp16): out = (H @ Wd^T) * down_s  (fp32 out)
// 128x64 tile, 128 threads (2 waves stacked in m, each 64x64 -> LDS traffic
// per FLOP unchanged), BK=64 (88 K-iters), LDS 24KB, grid 1024 -> 4-6
// resident blocks/CU (was GRID-limited to 2 at 512 blocks).  R0 2-barrier
// structure, swz8 layout (128B f16 rows, HW-verified conflict-free).
// Band order: 16 m-tiles inner x 32 n-tiles; XCD-chunked (1024 = 8*128).
// ---------------------------------------------------------------------------
__global__ __launch_bounds__(128, 2)
void gemm_down(const _Float16* __restrict__ Hm,
               const _Float16* __restrict__ Wd,
               const float* __restrict__ dsc,
               float* __restrict__ out) {
    __shared__ _Float16 As[128 * BK];   // 16KB
    __shared__ _Float16 Bs[ 64 * BK];   // 8KB

    // XCD-chunked bijective swizzle (nwg = 1024 = 8*128)
    const int pid = (blockIdx.x % 8) * 128 + blockIdx.x / 8;
    const int loc = pid & 511;
    const int bm  = ((pid >> 9) * 16 + (loc & 15)) * 128;
    const int bn  = (loc >> 4) * 64;

    const int tid  = threadIdx.x;          // 0..127
    const int lane = tid & 63;
    const int wave = tid >> 6;             // 0..1
    const int wm   = wave * 64;
    const int l15  = lane & 15;
    const int lq   = lane >> 4;

    // staging (swz8, 128B rows): A = 1024 slots (8 rounds of 128 thr),
    // B = 512 slots (4 rounds).
    int rS[8], sS[8];
    #pragma unroll
    for (int j = 0; j < 8; ++j) {
        const int f = tid + 128 * j;
        rS[j] = f >> 3;
        sS[j] = (((f & 7) - (f >> 3)) & 7) * 8;   // f16 elements
    }

    f32x4 acc[4][4] = {};

    for (int k0 = 0; k0 < INTER; k0 += BK) {
        #pragma unroll
        for (int j = 0; j < 8; ++j) {
            const int f = tid + 128 * j;
            GLDS16(Hm + (size_t)(bm + rS[j]) * INTER + k0 + sS[j], &As[f * 8]);
        }
        #pragma unroll
        for (int j = 0; j < 4; ++j) {
            const int f = tid + 128 * j;
            GLDS16(Wd + (size_t)(bn + rS[j]) * INTER + k0 + sS[j], &Bs[f * 8]);
        }
        __syncthreads();

        #pragma unroll
        for (int ks = 0; ks < 2; ++ks) {
            const int q = ks * 4 + lq;
            f16x8 a[4];
            #pragma unroll
            for (int im = 0; im < 4; ++im)
                a[im] = *(const f16x8*)&As[swz8(wm + im * 16 + l15, q) * 8];
            #pragma unroll
            for (int jn = 0; jn < 4; ++jn) {
                f16x8 b = *(const f16x8*)&Bs[swz8(jn * 16 + l15, q) * 8];
                #pragma unroll
                for (int im = 0; im < 4; ++im)
                    acc[im][jn] = __builtin_amdgcn_mfma_f32_16x16x32_f16(a[im], b, acc[im][jn], 0, 0, 0);
            }
        }
        __syncthreads();
    }

    #pragma unroll
    for (int jn = 0; jn < 4; ++jn) {
        const int col = bn + jn * 16 + l15;
        const float sd = dsc[col];
        #pragma unroll
        for (int im = 0; im < 4; ++im) {
            const int rbase = bm + wm + im * 16 + lq * 4;
            #pragma unroll
            for (int r = 0; r < 4; ++r)
                out[(size_t)(rbase + r) * HIDDEN + col] = acc[im][jn][r] * sd;
        }
    }
}

// ---------------------------------------------------------------------------
// launch
// ---------------------------------------------------------------------------
extern "C" void kernel_launch(void* const* d_in, const int* in_sizes, int n_in,
                              void* d_out, int out_size, void* d_ws, size_t ws_size,
                              hipStream_t stream) {
    const float* x   = (const float*)d_in[0];
    const float* gw  = (const float*)d_in[1];
    const float* uw  = (const float*)d_in[2];
    const float* dw  = (const float*)d_in[3];
    const float* gsc = (const float*)d_in[4];
    const float* usc = (const float*)d_in[5];
    const float* dsc = (const float*)d_in[6];
    float* out = (float*)d_out;

    // workspace layout:
    //   Xq  i8  @          0 :  8,388,608
    //   Wg8 i8  @  8,388,608 : 11,534,336
    //   Wu8 i8  @ 19,922,944 : 11,534,336
    //   Wdh f16 @ 31,457,280 : 23,068,672
    //   Hm  f16 @ 54,525,952 : 46,137,344
    //   xs  f32 @100,663,296 :     16,384
    char* ws = (char*)d_ws;
    int8_t*   Xq  = (int8_t*)(ws);
    int8_t*   Wg8 = (int8_t*)(ws + 8388608ull);
    int8_t*   Wu8 = (int8_t*)(ws + 19922944ull);
    _Float16* Wdh = (_Float16*)(ws + 31457280ull);
    _Float16* Hm  = (_Float16*)(ws + 54525952ull);
    float*    xs  = (float*)(ws + 100663296ull);

    prepass<<<TOKENS + 2048, 256, 0, stream>>>(
        x, (const float4*)gw, (const float4*)uw, (const float4*)dw,
        Xq, xs, (int*)Wg8, (int*)Wu8, (f16x4*)Wdh);

    gemm_gateup<<<(INTER / 128) * (TOKENS / 128), 256, 0, stream>>>(
        Xq, Wg8, Wu8, xs, gsc, usc, Hm);
    gemm_down<<<(HIDDEN / 64) * (TOKENS / 128), 128, 0, stream>>>(
        Hm, Wdh, dsc, out);
}

// Round 6
// 387.160 us; speedup vs baseline: 1.0748x; 1.0748x over previous
//
#include <hip/hip_runtime.h>
#include <stdint.h>
#include <stddef.h>

#define HIDDEN 2048
#define INTER  5632
#define TOKENS 4096   // B*S = 2*2048
#define BKD    128    // f16 K-tile (down GEMM)  -> 2 half-tiles of 128B rows, 44 iters
#define BKI    128    // i8 K-tile (gateup GEMM) -> 128B rows, 16 iters

typedef __attribute__((ext_vector_type(8))) _Float16 f16x8;
typedef __attribute__((ext_vector_type(4))) _Float16 f16x4;
typedef __attribute__((ext_vector_type(4))) float    f32x4;
typedef __attribute__((ext_vector_type(4))) int      i32x4;

// 128B-row LDS swizzle, period-8 row rotation: global segment q of row r lives
// at slot r*8 + ((q + r) & 7).  ds_read_b128 conflict unit is an 8-lane phase
// (8 x 16B = all 32 banks): for fixed q, 8 consecutive rows map to 8 DISTINCT
// bank-quads -> conflict-free (HW-verified: SQ_LDS_BANK_CONFLICT = 0, R0-R5).
__device__ __forceinline__ int swz8(int row, int q) {
    return row * 8 + ((q + row) & 7);
}

#define GLDS16(g, l) __builtin_amdgcn_global_load_lds( \
    (__attribute__((address_space(1))) void*)(g), \
    (__attribute__((address_space(3))) void*)(l), 16, 0, 0)

// ---------------------------------------------------------------------------
// fused prepass: blocks [0,TOKENS) quantize x per-token to i8;
// blocks [TOKENS, TOKENS+2048) grid-stride convert weights
// ---------------------------------------------------------------------------
__global__ __launch_bounds__(256)
void prepass(const float* __restrict__ x,
             const float4* __restrict__ gw, const float4* __restrict__ uw,
             const float4* __restrict__ dw,
             int8_t* __restrict__ xq, float* __restrict__ xs,
             int* __restrict__ go, int* __restrict__ uo,
             f16x4* __restrict__ dno) {
    const int tid = threadIdx.x;
    if (blockIdx.x < TOKENS) {
        const int t = blockIdx.x;
        const float4* row = (const float4*)(x + (size_t)t * HIDDEN);
        float4 v0 = row[tid * 2];
        float4 v1 = row[tid * 2 + 1];
        float m = fmaxf(fmaxf(fabsf(v0.x), fabsf(v0.y)), fmaxf(fabsf(v0.z), fabsf(v0.w)));
        m = fmaxf(m, fmaxf(fmaxf(fabsf(v1.x), fabsf(v1.y)), fmaxf(fabsf(v1.z), fabsf(v1.w))));
        #pragma unroll
        for (int off = 32; off; off >>= 1)
            m = fmaxf(m, __shfl_xor(m, off, 64));
        __shared__ float wmax[4];
        if ((tid & 63) == 0) wmax[tid >> 6] = m;
        __syncthreads();
        m = fmaxf(fmaxf(wmax[0], wmax[1]), fmaxf(wmax[2], wmax[3]));
        m = fmaxf(m, 1e-20f);
        if (tid == 0) xs[t] = m * (1.0f / 127.0f);
        const float inv = 127.0f / m;
        float vals[8] = {v0.x, v0.y, v0.z, v0.w, v1.x, v1.y, v1.z, v1.w};
        int b[8];
        #pragma unroll
        for (int i = 0; i < 8; ++i) b[i] = (int)rintf(vals[i] * inv);
        int lo = (b[0] & 255) | ((b[1] & 255) << 8) | ((b[2] & 255) << 16) | (b[3] << 24);
        int hi = (b[4] & 255) | ((b[5] & 255) << 8) | ((b[6] & 255) << 16) | (b[7] << 24);
        ((int2*)(xq + (size_t)t * HIDDEN))[tid] = make_int2(lo, hi);
        return;
    }
    const int NW4 = INTER * HIDDEN / 4;
    int i = (blockIdx.x - TOKENS) * blockDim.x + tid;
    const int stride = 2048 * blockDim.x;
    for (; i < 3 * NW4; i += stride) {
        if (i < 2 * NW4) {
            const bool is_g = i < NW4;
            const int j = is_g ? i : i - NW4;
            float4 f = is_g ? gw[j] : uw[j];
            int p = ((int)(signed char)(int)f.x & 255)
                  | (((int)(signed char)(int)f.y & 255) << 8)
                  | (((int)(signed char)(int)f.z & 255) << 16)
                  | (((int)(signed char)(int)f.w) << 24);
            if (is_g) go[j] = p; else uo[j] = p;
        } else {
            const int j = i - 2 * NW4;
            float4 f = dw[j];
            f16x4 o;
            o.x = (_Float16)f.x; o.y = (_Float16)f.y;
            o.z = (_Float16)f.z; o.w = (_Float16)f.w;
            dno[j] = o;
        }
    }
}

// ---------------------------------------------------------------------------
// GEMM1 fused (i8): H = silu(G*xs*gs) * (U*xs*us)  (fp16 out)
// 256x128 tile, 512 thr (8 waves, 4Mx2N, wave tile 64x64 unchanged), BKI=128
// (16 K-iters), LDS 64KB single-buffer -> exactly 2 blocks/CU (same occupancy
// as the 105us R0 config, but 2x MFMA per drain and 2B staging/output vs 3B).
// R0 2-barrier schedule verbatim; swz8 layout verbatim (0 conflicts R0-R5).
// Grid 704 = 16m x 44n, XCD-chunked (704 = 8*88).
// ---------------------------------------------------------------------------
__global__ __launch_bounds__(512, 2)
void gemm_gateup(const int8_t* __restrict__ Xq,
                 const int8_t* __restrict__ Wg,
                 const int8_t* __restrict__ Wu,
                 const float* __restrict__ xs,
                 const float* __restrict__ gs,
                 const float* __restrict__ us,
                 _Float16* __restrict__ Hm) {
    __shared__ int8_t As [256 * BKI];   // 32KB
    __shared__ int8_t Bgs[128 * BKI];   // 16KB
    __shared__ int8_t Bus[128 * BKI];   // 16KB

    // XCD-chunked bijective swizzle (nwg = 704 = 8*88)
    const int pid = (blockIdx.x % 8) * 88 + blockIdx.x / 8;
    const int bm  = (pid & 15) * 256;    // 16 m-tiles (m fast -> band shares Wg/Wu panel)
    const int bn  = (pid >> 4) * 128;    // 44 n-tiles

    const int tid  = threadIdx.x;          // 0..511
    const int lane = tid & 63;
    const int wave = tid >> 6;             // 0..7
    const int wm   = (wave >> 1) * 64;     // 4 M-waves
    const int wn   = (wave & 1) * 64;      // 2 N-waves
    const int l15  = lane & 15;
    const int lq   = lane >> 4;

    // staging slots (16B each): A = 2048 (4 rounds of 512), B = 1024 (2 rounds)
    int rowA[4], sgA[4];
    #pragma unroll
    for (int j = 0; j < 4; ++j) {
        const int f = tid + 512 * j;
        rowA[j] = f >> 3;
        sgA[j]  = (((f & 7) - rowA[j]) & 7) * 16;
    }

    const int8_t* gA = Xq + (size_t)bm * HIDDEN;
    const int8_t* gG = Wg + (size_t)bn * HIDDEN;
    const int8_t* gU = Wu + (size_t)bn * HIDDEN;

    i32x4 accg[4][4] = {};
    i32x4 accu[4][4] = {};

    for (int k0 = 0; k0 < HIDDEN; k0 += BKI) {
        #pragma unroll
        for (int j = 0; j < 4; ++j) {   // A: rows 0..255
            const int f = tid + 512 * j;
            GLDS16(gA + (size_t)rowA[j] * HIDDEN + k0 + sgA[j], &As[f * 16]);
        }
        #pragma unroll
        for (int j = 0; j < 2; ++j) {   // Bg, Bu: rows 0..127
            const int f = tid + 512 * j;
            const size_t off = (size_t)rowA[j] * HIDDEN + k0 + sgA[j];
            GLDS16(gG + off, &Bgs[f * 16]);
            GLDS16(gU + off, &Bus[f * 16]);
        }
        __syncthreads();

        #pragma unroll
        for (int ks = 0; ks < 2; ++ks) {
            const int q = ks * 4 + lq;     // segment for this MFMA k-step
            i32x4 a[4];
            #pragma unroll
            for (int im = 0; im < 4; ++im)
                a[im] = *(const i32x4*)&As[swz8(wm + im * 16 + l15, q) * 16];
            #pragma unroll
            for (int jn = 0; jn < 4; ++jn) {
                i32x4 bg = *(const i32x4*)&Bgs[swz8(wn + jn * 16 + l15, q) * 16];
                i32x4 bu = *(const i32x4*)&Bus[swz8(wn + jn * 16 + l15, q) * 16];
                #pragma unroll
                for (int im = 0; im < 4; ++im) {
                    accg[im][jn] = __builtin_amdgcn_mfma_i32_16x16x64_i8(a[im], bg, accg[im][jn], 0, 0, 0);
                    accu[im][jn] = __builtin_amdgcn_mfma_i32_16x16x64_i8(a[im], bu, accu[im][jn], 0, 0, 0);
                }
            }
        }
        __syncthreads();
    }

    #pragma unroll
    for (int jn = 0; jn < 4; ++jn) {
        const int col = bn + wn + jn * 16 + l15;
        const float sg = gs[col];
        const float su = us[col];
        #pragma unroll
        for (int im = 0; im < 4; ++im) {
            const int rbase = bm + wm + im * 16 + lq * 4;
            #pragma unroll
            for (int r = 0; r < 4; ++r) {
                const int row = rbase + r;
                const float st = xs[row];
                float g = (float)accg[im][jn][r] * st * sg;
                float u = (float)accu[im][jn][r] * st * su;
                float h = (g / (1.0f + __expf(-g))) * u;
                Hm[(size_t)row * INTER + col] = (_Float16)h;
            }
        }
    }
}

// ---------------------------------------------------------------------------
// GEMM2 (fp16): out = (H @ Wd^T) * down_s  (fp32 out)
// 128x128 tile, 256 thr, BKD=128 via two swz8 half-tiles per matrix (each
// [128][64 f16] = 16KB) -> 44 K-iters (was 88), LDS 64KB -> 2 blocks/CU
// (grid-limited to 2 before anyway: occupancy constant, drains halved).
// R0 2-barrier schedule verbatim; swz8 layout verbatim.  Grid 512 = 8*64.
// ---------------------------------------------------------------------------
__global__ __launch_bounds__(256, 2)
void gemm_down(const _Float16* __restrict__ Hm,
               const _Float16* __restrict__ Wd,
               const float* __restrict__ dsc,
               float* __restrict__ out) {
    __shared__ _Float16 As0[128 * 64];   // k0..63   16KB
    __shared__ _Float16 As1[128 * 64];   // k64..127 16KB
    __shared__ _Float16 Bs0[128 * 64];
    __shared__ _Float16 Bs1[128 * 64];

    // XCD-chunked bijective swizzle (nwg = 512 = 8*64)
    const int pid = (blockIdx.x % 8) * 64 + blockIdx.x / 8;
    const int loc = pid & 255;
    const int bm  = ((pid >> 8) * 16 + (loc & 15)) * 128;
    const int bn  = (loc >> 4) * 128;

    const int tid  = threadIdx.x;
    const int lane = tid & 63;
    const int wave = tid >> 6;
    const int wm   = (wave >> 1) * 64;
    const int wn   = (wave & 1) * 64;
    const int l15  = lane & 15;
    const int lq   = lane >> 4;

    // staging: per half-tile 1024 slots (4 rounds of 256 thr)
    int rS[4], sS[4];
    #pragma unroll
    for (int j = 0; j < 4; ++j) {
        const int f = tid + 256 * j;
        rS[j] = f >> 3;
        sS[j] = (((f & 7) - (f >> 3)) & 7) * 8;   // f16 elements, 16B segs
    }

    const _Float16* gA = Hm + (size_t)bm * INTER;
    const _Float16* gB = Wd + (size_t)bn * INTER;

    f32x4 acc[4][4] = {};

    for (int k0 = 0; k0 < INTER; k0 += BKD) {
        #pragma unroll
        for (int j = 0; j < 4; ++j) {
            const int f = tid + 256 * j;
            const size_t oA = (size_t)rS[j] * INTER + k0 + sS[j];
            GLDS16(gA + oA,      &As0[f * 8]);
            GLDS16(gA + oA + 64, &As1[f * 8]);
            const size_t oB = (size_t)rS[j] * INTER + k0 + sS[j];
            GLDS16(gB + oB,      &Bs0[f * 8]);
            GLDS16(gB + oB + 64, &Bs1[f * 8]);
        }
        __syncthreads();

        #pragma unroll
        for (int ks = 0; ks < 4; ++ks) {
            const _Float16* A_ = (ks < 2) ? As0 : As1;
            const _Float16* B_ = (ks < 2) ? Bs0 : Bs1;
            const int q = (ks & 1) * 4 + lq;
            f16x8 a[4];
            #pragma unroll
            for (int im = 0; im < 4; ++im)
                a[im] = *(const f16x8*)&A_[swz8(wm + im * 16 + l15, q) * 8];
            #pragma unroll
            for (int jn = 0; jn < 4; ++jn) {
                f16x8 b = *(const f16x8*)&B_[swz8(wn + jn * 16 + l15, q) * 8];
                #pragma unroll
                for (int im = 0; im < 4; ++im)
                    acc[im][jn] = __builtin_amdgcn_mfma_f32_16x16x32_f16(a[im], b, acc[im][jn], 0, 0, 0);
            }
        }
        __syncthreads();
    }

    #pragma unroll
    for (int jn = 0; jn < 4; ++jn) {
        const int col = bn + wn + jn * 16 + l15;
        const float sd = dsc[col];
        #pragma unroll
        for (int im = 0; im < 4; ++im) {
            const int rbase = bm + wm + im * 16 + lq * 4;
            #pragma unroll
            for (int r = 0; r < 4; ++r)
                out[(size_t)(rbase + r) * HIDDEN + col] = acc[im][jn][r] * sd;
        }
    }
}

// ---------------------------------------------------------------------------
// launch
// ---------------------------------------------------------------------------
extern "C" void kernel_launch(void* const* d_in, const int* in_sizes, int n_in,
                              void* d_out, int out_size, void* d_ws, size_t ws_size,
                              hipStream_t stream) {
    const float* x   = (const float*)d_in[0];
    const float* gw  = (const float*)d_in[1];
    const float* uw  = (const float*)d_in[2];
    const float* dw  = (const float*)d_in[3];
    const float* gsc = (const float*)d_in[4];
    const float* usc = (const float*)d_in[5];
    const float* dsc = (const float*)d_in[6];
    float* out = (float*)d_out;

    // workspace layout:
    //   Xq  i8  @          0 :  8,388,608
    //   Wg8 i8  @  8,388,608 : 11,534,336
    //   Wu8 i8  @ 19,922,944 : 11,534,336
    //   Wdh f16 @ 31,457,280 : 23,068,672
    //   Hm  f16 @ 54,525,952 : 46,137,344
    //   xs  f32 @100,663,296 :     16,384
    char* ws = (char*)d_ws;
    int8_t*   Xq  = (int8_t*)(ws);
    int8_t*   Wg8 = (int8_t*)(ws + 8388608ull);
    int8_t*   Wu8 = (int8_t*)(ws + 19922944ull);
    _Float16* Wdh = (_Float16*)(ws + 31457280ull);
    _Float16* Hm  = (_Float16*)(ws + 54525952ull);
    float*    xs  = (float*)(ws + 100663296ull);

    prepass<<<TOKENS + 2048, 256, 0, stream>>>(
        x, (const float4*)gw, (const float4*)uw, (const float4*)dw,
        Xq, xs, (int*)Wg8, (int*)Wu8, (f16x4*)Wdh);

    gemm_gateup<<<(INTER / 128) * (TOKENS / 256), 512, 0, stream>>>(
        Xq, Wg8, Wu8, xs, gsc, usc, Hm);
    gemm_down<<<(HIDDEN / 128) * (TOKENS / 128), 256, 0, stream>>>(
        Hm, Wdh, dsc, out);
}

// Round 7
// 371.243 us; speedup vs baseline: 1.1209x; 1.0429x over previous
//
#include <hip/hip_runtime.h>
#include <stdint.h>
#include <stddef.h>

#define HIDDEN 2048
#define INTER  5632
#define TOKENS 4096   // B*S = 2*2048
#define BKD    128    // f16 K-tile (down GEMM)  -> 2 half-tiles of 128B rows, 44 iters
#define BKI    128    // i8 K-tile (gateup GEMM) -> 128B rows, 16 iters

typedef __attribute__((ext_vector_type(8))) _Float16 f16x8;
typedef __attribute__((ext_vector_type(4))) _Float16 f16x4;
typedef __attribute__((ext_vector_type(4))) float    f32x4;
typedef __attribute__((ext_vector_type(4))) int      i32x4;

// 128B-row LDS swizzle, period-8 row rotation: global segment q of row r lives
// at slot r*8 + ((q + r) & 7).  ds_read_b128 conflict unit is an 8-lane phase
// (8 x 16B = all 32 banks): for fixed q, 8 consecutive rows map to 8 DISTINCT
// bank-quads -> conflict-free (HW-verified: SQ_LDS_BANK_CONFLICT = 0, R0-R6).
__device__ __forceinline__ int swz8(int row, int q) {
    return row * 8 + ((q + row) & 7);
}

#define GLDS16(g, l) __builtin_amdgcn_global_load_lds( \
    (__attribute__((address_space(1))) void*)(g), \
    (__attribute__((address_space(3))) void*)(l), 16, 0, 0)

__device__ __forceinline__ int pack4i8(float4 f) {
    return ((int)(signed char)(int)f.x & 255)
         | (((int)(signed char)(int)f.y & 255) << 8)
         | (((int)(signed char)(int)f.z & 255) << 16)
         | (((int)(signed char)(int)f.w) << 24);
}

// ---------------------------------------------------------------------------
// fused prepass, BW-optimized rewrite (prepass+overhead measured as a
// constant ~170us pool across R0-R6; roofline for this kernel is ~36us).
//   blocks [0,1024):      token quant, one WAVE per token (no barriers, no
//                         LDS round-trip; 32 floats/lane in regs).
//   blocks [1024,3072):   weight convert, 64B-units, 16B packed stores.
// ---------------------------------------------------------------------------
__global__ __launch_bounds__(256)
void prepass(const float* __restrict__ x,
             const float4* __restrict__ gw, const float4* __restrict__ uw,
             const float4* __restrict__ dw,
             int8_t* __restrict__ xq, float* __restrict__ xs,
             int* __restrict__ go, int* __restrict__ uo,
             _Float16* __restrict__ dno) {
    const int tid = threadIdx.x;
    if (blockIdx.x < 1024) {
        // ---- token quantization: wave-per-token ----
        const int wave = tid >> 6;
        const int lane = tid & 63;
        const int t    = blockIdx.x * 4 + wave;
        const float4* row = (const float4*)(x + (size_t)t * HIDDEN); // 512 f4
        float4 v[8];
        #pragma unroll
        for (int j = 0; j < 8; ++j) v[j] = row[lane + 64 * j];
        float m = 0.0f;
        #pragma unroll
        for (int j = 0; j < 8; ++j) {
            m = fmaxf(m, fmaxf(fmaxf(fabsf(v[j].x), fabsf(v[j].y)),
                               fmaxf(fabsf(v[j].z), fabsf(v[j].w))));
        }
        #pragma unroll
        for (int off = 32; off; off >>= 1)
            m = fmaxf(m, __shfl_xor(m, off, 64));
        m = fmaxf(m, 1e-20f);
        if (lane == 0) xs[t] = m * (1.0f / 127.0f);
        const float inv = 127.0f / m;
        int* oq = (int*)(xq + (size_t)t * HIDDEN);
        #pragma unroll
        for (int j = 0; j < 8; ++j) {
            float4 f = v[j];
            f.x *= inv; f.y *= inv; f.z *= inv; f.w *= inv;
            float4 r;
            r.x = rintf(f.x); r.y = rintf(f.y); r.z = rintf(f.z); r.w = rintf(f.w);
            oq[lane + 64 * j] = pack4i8(r);
        }
        return;
    }
    // ---- weight conversion: 64B units ----
    // unit u < NA:        gw[u*4 .. u*4+3]  -> int4 store to go
    // NA <= u < 2NA:      uw                -> uo
    // 2NA <= u < 2NA+NC:  dw[(u-2NA)*2 ..]  -> f16x8 store to dno
    const int NA = INTER * HIDDEN / 16;   // 720896
    const int NC = INTER * HIDDEN / 8;    // 1441792
    const int stride = 2048 * 256;
    for (int u = (blockIdx.x - 1024) * 256 + tid; u < 2 * NA + NC; u += stride) {
        if (u < 2 * NA) {
            const bool is_g = u < NA;
            const int j = is_g ? u : u - NA;
            const float4* src = (is_g ? gw : uw) + (size_t)j * 4;
            float4 f0 = src[0], f1 = src[1], f2 = src[2], f3 = src[3];
            int4 p;
            p.x = pack4i8(f0); p.y = pack4i8(f1);
            p.z = pack4i8(f2); p.w = pack4i8(f3);
            ((int4*)(is_g ? go : uo))[j] = p;
        } else {
            const int j = u - 2 * NA;
            const float4* src = dw + (size_t)j * 2;
            float4 a = src[0], b = src[1];
            f16x8 o;
            o[0] = (_Float16)a.x; o[1] = (_Float16)a.y;
            o[2] = (_Float16)a.z; o[3] = (_Float16)a.w;
            o[4] = (_Float16)b.x; o[5] = (_Float16)b.y;
            o[6] = (_Float16)b.z; o[7] = (_Float16)b.w;
            *(f16x8*)(dno + (size_t)j * 8) = o;
        }
    }
}

// ---------------------------------------------------------------------------
// GEMM1 fused (i8): H = silu(G*xs*gs) * (U*xs*us)  (fp16 out)
// R4-exact config (proven <=101us): 128x128 tile, 256 thr, BKI=128 (16
// K-iters), LDS 48KB, 2 blocks/CU, R0 2-barrier compiler schedule, swz8
// layout, XCD-chunked grid (1408 = 8*176).  R1/R3 in-block pipelines and
// R6's 256-wide block all regressed -- this is the measured local optimum.
// ---------------------------------------------------------------------------
__global__ __launch_bounds__(256, 2)
void gemm_gateup(const int8_t* __restrict__ Xq,
                 const int8_t* __restrict__ Wg,
                 const int8_t* __restrict__ Wu,
                 const float* __restrict__ xs,
                 const float* __restrict__ gs,
                 const float* __restrict__ us,
                 _Float16* __restrict__ Hm) {
    __shared__ int8_t As [128 * BKI];
    __shared__ int8_t Bgs[128 * BKI];
    __shared__ int8_t Bus[128 * BKI];

    const int pid   = (blockIdx.x % 8) * 176 + blockIdx.x / 8;
    const int local = pid % (16 * 44);
    const int bm    = ((pid / (16 * 44)) * 16 + (local & 15)) * 128;
    const int bn    = (local >> 4) * 128;

    const int tid  = threadIdx.x;
    const int lane = tid & 63;
    const int wave = tid >> 6;
    const int wm   = (wave >> 1) * 64;
    const int wn   = (wave & 1) * 64;
    const int l15  = lane & 15;
    const int lq   = lane >> 4;

    int rowA[4], sgA[4];
    #pragma unroll
    for (int j = 0; j < 4; ++j) {
        const int f = tid + 256 * j;
        rowA[j] = f >> 3;
        sgA[j]  = (((f & 7) - rowA[j]) & 7) * 16;
    }

    i32x4 accg[4][4] = {};
    i32x4 accu[4][4] = {};

    for (int k0 = 0; k0 < HIDDEN; k0 += BKI) {
        #pragma unroll
        for (int j = 0; j < 4; ++j) {
            const int f = tid + 256 * j;
            const int8_t* pX = Xq + (size_t)(bm + rowA[j]) * HIDDEN + k0 + sgA[j];
            const int8_t* pG = Wg + (size_t)(bn + rowA[j]) * HIDDEN + k0 + sgA[j];
            const int8_t* pU = Wu + (size_t)(bn + rowA[j]) * HIDDEN + k0 + sgA[j];
            GLDS16(pX, &As [f * 16]);
            GLDS16(pG, &Bgs[f * 16]);
            GLDS16(pU, &Bus[f * 16]);
        }
        __syncthreads();

        #pragma unroll
        for (int ks = 0; ks < 2; ++ks) {
            const int q = ks * 4 + lq;
            i32x4 a[4];
            #pragma unroll
            for (int im = 0; im < 4; ++im)
                a[im] = *(const i32x4*)&As[swz8(wm + im * 16 + l15, q) * 16];
            #pragma unroll
            for (int jn = 0; jn < 4; ++jn) {
                i32x4 bg = *(const i32x4*)&Bgs[swz8(wn + jn * 16 + l15, q) * 16];
                i32x4 bu = *(const i32x4*)&Bus[swz8(wn + jn * 16 + l15, q) * 16];
                #pragma unroll
                for (int im = 0; im < 4; ++im) {
                    accg[im][jn] = __builtin_amdgcn_mfma_i32_16x16x64_i8(a[im], bg, accg[im][jn], 0, 0, 0);
                    accu[im][jn] = __builtin_amdgcn_mfma_i32_16x16x64_i8(a[im], bu, accu[im][jn], 0, 0, 0);
                }
            }
        }
        __syncthreads();
    }

    #pragma unroll
    for (int jn = 0; jn < 4; ++jn) {
        const int col = bn + wn + jn * 16 + l15;
        const float sg = gs[col];
        const float su = us[col];
        #pragma unroll
        for (int im = 0; im < 4; ++im) {
            const int rbase = bm + wm + im * 16 + lq * 4;
            #pragma unroll
            for (int r = 0; r < 4; ++r) {
                const int row = rbase + r;
                const float st = xs[row];
                float g = (float)accg[im][jn][r] * st * sg;
                float u = (float)accu[im][jn][r] * st * su;
                float h = (g / (1.0f + __expf(-g))) * u;
                Hm[(size_t)row * INTER + col] = (_Float16)h;
            }
        }
    }
}

// ---------------------------------------------------------------------------
// GEMM2 (fp16): out = (H @ Wd^T) * down_s  (fp32 out)
// R6-exact config (inferred ~82us, was 101 at BK=64): 128x128 tile, 256 thr,
// BKD=128 via two swz8 half-tiles per matrix -> 44 K-iters, LDS 64KB,
// 2 blocks/CU (constant), drains per unit-K halved.  Grid 512 = 8*64.
// ---------------------------------------------------------------------------
__global__ __launch_bounds__(256, 2)
void gemm_down(const _Float16* __restrict__ Hm,
               const _Float16* __restrict__ Wd,
               const float* __restrict__ dsc,
               float* __restrict__ out) {
    __shared__ _Float16 As0[128 * 64];   // k0..63   16KB
    __shared__ _Float16 As1[128 * 64];   // k64..127 16KB
    __shared__ _Float16 Bs0[128 * 64];
    __shared__ _Float16 Bs1[128 * 64];

    const int pid = (blockIdx.x % 8) * 64 + blockIdx.x / 8;
    const int loc = pid & 255;
    const int bm  = ((pid >> 8) * 16 + (loc & 15)) * 128;
    const int bn  = (loc >> 4) * 128;

    const int tid  = threadIdx.x;
    const int lane = tid & 63;
    const int wave = tid >> 6;
    const int wm   = (wave >> 1) * 64;
    const int wn   = (wave & 1) * 64;
    const int l15  = lane & 15;
    const int lq   = lane >> 4;

    int rS[4], sS[4];
    #pragma unroll
    for (int j = 0; j < 4; ++j) {
        const int f = tid + 256 * j;
        rS[j] = f >> 3;
        sS[j] = (((f & 7) - (f >> 3)) & 7) * 8;   // f16 elements, 16B segs
    }

    const _Float16* gA = Hm + (size_t)bm * INTER;
    const _Float16* gB = Wd + (size_t)bn * INTER;

    f32x4 acc[4][4] = {};

    for (int k0 = 0; k0 < INTER; k0 += BKD) {
        #pragma unroll
        for (int j = 0; j < 4; ++j) {
            const int f = tid + 256 * j;
            const size_t oA = (size_t)rS[j] * INTER + k0 + sS[j];
            GLDS16(gA + oA,      &As0[f * 8]);
            GLDS16(gA + oA + 64, &As1[f * 8]);
            GLDS16(gB + oA,      &Bs0[f * 8]);
            GLDS16(gB + oA + 64, &Bs1[f * 8]);
        }
        __syncthreads();

        #pragma unroll
        for (int ks = 0; ks < 4; ++ks) {
            const _Float16* A_ = (ks < 2) ? As0 : As1;
            const _Float16* B_ = (ks < 2) ? Bs0 : Bs1;
            const int q = (ks & 1) * 4 + lq;
            f16x8 a[4];
            #pragma unroll
            for (int im = 0; im < 4; ++im)
                a[im] = *(const f16x8*)&A_[swz8(wm + im * 16 + l15, q) * 8];
            #pragma unroll
            for (int jn = 0; jn < 4; ++jn) {
                f16x8 b = *(const f16x8*)&B_[swz8(wn + jn * 16 + l15, q) * 8];
                #pragma unroll
                for (int im = 0; im < 4; ++im)
                    acc[im][jn] = __builtin_amdgcn_mfma_f32_16x16x32_f16(a[im], b, acc[im][jn], 0, 0, 0);
            }
        }
        __syncthreads();
    }

    #pragma unroll
    for (int jn = 0; jn < 4; ++jn) {
        const int col = bn + wn + jn * 16 + l15;
        const float sd = dsc[col];
        #pragma unroll
        for (int im = 0; im < 4; ++im) {
            const int rbase = bm + wm + im * 16 + lq * 4;
            #pragma unroll
            for (int r = 0; r < 4; ++r)
                out[(size_t)(rbase + r) * HIDDEN + col] = acc[im][jn][r] * sd;
        }
    }
}

// ---------------------------------------------------------------------------
// launch
// ---------------------------------------------------------------------------
extern "C" void kernel_launch(void* const* d_in, const int* in_sizes, int n_in,
                              void* d_out, int out_size, void* d_ws, size_t ws_size,
                              hipStream_t stream) {
    const float* x   = (const float*)d_in[0];
    const float* gw  = (const float*)d_in[1];
    const float* uw  = (const float*)d_in[2];
    const float* dw  = (const float*)d_in[3];
    const float* gsc = (const float*)d_in[4];
    const float* usc = (const float*)d_in[5];
    const float* dsc = (const float*)d_in[6];
    float* out = (float*)d_out;

    // workspace layout:
    //   Xq  i8  @          0 :  8,388,608
    //   Wg8 i8  @  8,388,608 : 11,534,336
    //   Wu8 i8  @ 19,922,944 : 11,534,336
    //   Wdh f16 @ 31,457,280 : 23,068,672
    //   Hm  f16 @ 54,525,952 : 46,137,344
    //   xs  f32 @100,663,296 :     16,384
    char* ws = (char*)d_ws;
    int8_t*   Xq  = (int8_t*)(ws);
    int8_t*   Wg8 = (int8_t*)(ws + 8388608ull);
    int8_t*   Wu8 = (int8_t*)(ws + 19922944ull);
    _Float16* Wdh = (_Float16*)(ws + 31457280ull);
    _Float16* Hm  = (_Float16*)(ws + 54525952ull);
    float*    xs  = (float*)(ws + 100663296ull);

    prepass<<<1024 + 2048, 256, 0, stream>>>(
        x, (const float4*)gw, (const float4*)uw, (const float4*)dw,
        Xq, xs, (int*)Wg8, (int*)Wu8, Wdh);

    gemm_gateup<<<(INTER / 128) * (TOKENS / 128), 256, 0, stream>>>(
        Xq, Wg8, Wu8, xs, gsc, usc, Hm);
    gemm_down<<<(HIDDEN / 128) * (TOKENS / 128), 256, 0, stream>>>(
        Hm, Wdh, dsc, out);
}